// Round 6
// baseline (185.969 us; speedup 1.0000x reference)
//
#include <hip/hip_runtime.h>
#include <math.h>

#define PI_F 3.14159265358979323846f

// ---------- complex helpers (float2 as complex) ----------
__device__ __forceinline__ float2 cmul2(float2 a, float2 b) {
    return make_float2(a.x * b.x - a.y * b.y, a.x * b.y + a.y * b.x);
}
// u*a + v*b
__device__ __forceinline__ float2 cmac2(float2 u, float2 a, float2 v, float2 b) {
    float2 r;
    r.x = u.x * a.x - u.y * a.y + v.x * b.x - v.y * b.y;
    r.y = u.x * a.y + u.y * a.x + v.x * b.y + v.y * b.x;
    return r;
}

struct M4 { float2 u00, u01, u10, u11; };

__device__ __forceinline__ M4 mmul4(const M4& A, const M4& B) {
    M4 R;
    R.u00 = cmac2(A.u00, B.u00, A.u01, B.u10);
    R.u01 = cmac2(A.u00, B.u01, A.u01, B.u11);
    R.u10 = cmac2(A.u10, B.u00, A.u11, B.u10);
    R.u11 = cmac2(A.u10, B.u01, A.u11, B.u11);
    return R;
}
__device__ __forceinline__ M4 mry(float t) {
    float c = cosf(0.5f * t), s = sinf(0.5f * t);
    M4 R; R.u00 = {c, 0}; R.u01 = {-s, 0}; R.u10 = {s, 0}; R.u11 = {c, 0};
    return R;
}
__device__ __forceinline__ M4 mrz(float t) {
    float c = cosf(0.5f * t), s = sinf(0.5f * t);
    M4 R; R.u00 = {c, -s}; R.u01 = {0, 0}; R.u10 = {0, 0}; R.u11 = {c, s};
    return R;
}
// Rot(phi, theta, omega) = RZ(omega) @ RY(theta) @ RZ(phi)
__device__ __forceinline__ M4 mrot(float phi, float th, float om) {
    return mmul4(mmul4(mrz(om), mry(th)), mrz(phi));
}

__device__ __forceinline__ float2 shflx(float2 v, int mask) {
    return make_float2(__shfl_xor(v.x, mask, 64), __shfl_xor(v.y, mask, 64));
}

// load an M4 from wave-uniform global memory (compiler emits scalar loads)
__device__ __forceinline__ M4 ldm(const float* __restrict__ g) {
    M4 M;
    M.u00 = make_float2(g[0], g[1]); M.u01 = make_float2(g[2], g[3]);
    M.u10 = make_float2(g[4], g[5]); M.u11 = make_float2(g[6], g[7]);
    return M;
}

// ---------- register statevector: idx = lane*8 + r ----------
// idx bit b: b in [0,2] -> register bit b; b in [3,8] -> lane bit (b-3).
// wire w -> idx bit (8-w). Wires 0..5 = lane bits 5..0; wires 6,7,8 = reg bits 2,1,0.

// single-qubit dense gate on register bit TB
template <int TB>
__device__ __forceinline__ void rot_reg(const M4& U, float2 (&amp)[8]) {
#pragma unroll
    for (int r = 0; r < 8; r++)
        if (((r >> TB) & 1) == 0) {
            int r1 = r | (1 << TB);
            float2 a = amp[r], b = amp[r1];
            amp[r]  = cmac2(U.u00, a, U.u01, b);
            amp[r1] = cmac2(U.u10, a, U.u11, b);
        }
}

// single-qubit dense gate on lane bit LB
template <int LB>
__device__ __forceinline__ void rot_lane(const M4& U, float2 (&amp)[8], int lane) {
    bool hi = (lane >> LB) & 1;
    float2 cA = hi ? U.u11 : U.u00;
    float2 cB = hi ? U.u10 : U.u01;
#pragma unroll
    for (int r = 0; r < 8; r++) {
        float2 o = shflx(amp[r], 1 << LB);
        amp[r] = cmac2(cA, amp[r], cB, o);
    }
}

template <int WIRE>
__device__ __forceinline__ void rot1(const M4& U, float2 (&amp)[8], int lane) {
    constexpr int BIT = 8 - WIRE;
    if constexpr (BIT < 3) rot_reg<BIT>(U, amp);
    else rot_lane<BIT - 3>(U, amp, lane);
}

// ---------- specialized controlled rotations (target = reg bit TB) ----------

// controlled RX: [[c, -i s], [-i s, c]]
template <int CBIT, int TB>
__device__ __forceinline__ void crx_g(float c, float s, float2 (&amp)[8], int lane) {
    if constexpr (CBIT >= 3) {
        bool ct = (lane >> (CBIT - 3)) & 1;
        float cc = ct ? c : 1.f, ss = ct ? s : 0.f;
#pragma unroll
        for (int r = 0; r < 8; r++)
            if (((r >> TB) & 1) == 0) {
                int r1 = r | (1 << TB);
                float2 a = amp[r], b = amp[r1];
                amp[r]  = make_float2(cc * a.x + ss * b.y, cc * a.y - ss * b.x);
                amp[r1] = make_float2(ss * a.y + cc * b.x, cc * b.y - ss * a.x);
            }
    } else {
#pragma unroll
        for (int r = 0; r < 8; r++)
            if (((r >> CBIT) & 1) == 1 && ((r >> TB) & 1) == 0) {
                int r1 = r | (1 << TB);
                float2 a = amp[r], b = amp[r1];
                amp[r]  = make_float2(c * a.x + s * b.y, c * a.y - s * b.x);
                amp[r1] = make_float2(s * a.y + c * b.x, c * b.y - s * a.x);
            }
    }
}

// controlled RY: [[c, -s], [s, c]] (real)
template <int CBIT, int TB>
__device__ __forceinline__ void cry_g(float c, float s, float2 (&amp)[8], int lane) {
    if constexpr (CBIT >= 3) {
        bool ct = (lane >> (CBIT - 3)) & 1;
        float cc = ct ? c : 1.f, ss = ct ? s : 0.f;
#pragma unroll
        for (int r = 0; r < 8; r++)
            if (((r >> TB) & 1) == 0) {
                int r1 = r | (1 << TB);
                float2 a = amp[r], b = amp[r1];
                amp[r]  = make_float2(cc * a.x - ss * b.x, cc * a.y - ss * b.y);
                amp[r1] = make_float2(ss * a.x + cc * b.x, ss * a.y + cc * b.y);
            }
    } else {
#pragma unroll
        for (int r = 0; r < 8; r++)
            if (((r >> CBIT) & 1) == 1 && ((r >> TB) & 1) == 0) {
                int r1 = r | (1 << TB);
                float2 a = amp[r], b = amp[r1];
                amp[r]  = make_float2(c * a.x - s * b.x, c * a.y - s * b.y);
                amp[r1] = make_float2(s * a.x + c * b.x, s * a.y + c * b.y);
            }
    }
}

// controlled RZ: diag(e, conj(e)), e = c - i s
template <int CBIT, int TB>
__device__ __forceinline__ void crz_g(float c, float s, float2 (&amp)[8], int lane) {
    if constexpr (CBIT >= 3) {
        bool ct = (lane >> (CBIT - 3)) & 1;
        float cc = ct ? c : 1.f, ss = ct ? s : 0.f;
#pragma unroll
        for (int r = 0; r < 8; r++)
            if (((r >> TB) & 1) == 0) {
                int r1 = r | (1 << TB);
                float2 a = amp[r], b = amp[r1];
                amp[r]  = make_float2(cc * a.x + ss * a.y, cc * a.y - ss * a.x);
                amp[r1] = make_float2(cc * b.x - ss * b.y, cc * b.y + ss * b.x);
            }
    } else {
#pragma unroll
        for (int r = 0; r < 8; r++)
            if (((r >> CBIT) & 1) == 1 && ((r >> TB) & 1) == 0) {
                int r1 = r | (1 << TB);
                float2 a = amp[r], b = amp[r1];
                amp[r]  = make_float2(c * a.x + s * a.y, c * a.y - s * a.x);
                amp[r1] = make_float2(c * b.x - s * b.y, c * b.y + s * b.x);
            }
    }
}

template <int CW, int TW>
__device__ __forceinline__ void cnotg(float2 (&amp)[8], int lane) {
    constexpr int CBIT = 8 - CW, TBIT = 8 - TW;
    if constexpr (CBIT < 3 && TBIT < 3) {
#pragma unroll
        for (int r = 0; r < 8; r++)
            if (((r >> CBIT) & 1) == 1 && ((r >> TBIT) & 1) == 0) {
                int r1 = r | (1 << TBIT);
                float2 t = amp[r]; amp[r] = amp[r1]; amp[r1] = t;
            }
    } else if constexpr (CBIT >= 3 && TBIT < 3) {
        bool c = (lane >> (CBIT - 3)) & 1;
#pragma unroll
        for (int r = 0; r < 8; r++)
            if (((r >> TBIT) & 1) == 0) {
                int r1 = r | (1 << TBIT);
                float2 t0 = amp[r], t1 = amp[r1];
                amp[r]  = c ? t1 : t0;
                amp[r1] = c ? t0 : t1;
            }
    } else if constexpr (CBIT < 3 && TBIT >= 3) {
#pragma unroll
        for (int r = 0; r < 8; r++)
            if (((r >> CBIT) & 1) == 1) {
                amp[r] = shflx(amp[r], 1 << (TBIT - 3));
            }
    } else {
        bool c = (lane >> (CBIT - 3)) & 1;
#pragma unroll
        for (int r = 0; r < 8; r++) {
            float2 o = shflx(amp[r], 1 << (TBIT - 3));
            amp[r] = c ? o : amp[r];
        }
    }
}

// StronglyEntanglingLayers, L=1, 3 wires; gm = 3 precomputed dense Rot matrices
template <int W0, int W1, int W2>
__device__ __forceinline__ void sel3m(const float* __restrict__ gm, float2 (&amp)[8], int lane) {
    rot1<W0>(ldm(gm),      amp, lane);
    rot1<W1>(ldm(gm + 8),  amp, lane);
    rot1<W2>(ldm(gm + 16), amp, lane);
    cnotg<W0, W1>(amp, lane);
    cnotg<W1, W2>(amp, lane);
    cnotg<W2, W0>(amp, lane);
}

// gm layout (floats): [0..7] (c,s) x4 ctrl gates; [8..31] strong[0]; [32..55] strong[1]; [56..79] update
template <int I>
__device__ __forceinline__ void block_i(float2 (&amp)[8], float cx, float sx, float cy1, float sy1,
                                        float cz, float sz, float cy2, float sy2,
                                        const float* __restrict__ gm, int lane) {
    crx_g<4 - I, 1>(cx,  sx,  amp, lane);
    cry_g<8 - I, 1>(cy1, sy1, amp, lane);
    crz_g<4 - I, 0>(cz,  sz,  amp, lane);
    cry_g<8 - I, 0>(cy2, sy2, amp, lane);
    sel3m<I, 4 + I, 7>(gm + 8,  amp, lane);   // strong[0]
    sel3m<7, 4 + I, 8>(gm + 32, amp, lane);   // strong[1]
}

// ---------- kernel A: feature MLPs + prep block ----------
// Blocks [0,nodeBlocks): node MLP (IN=8). [nodeBlocks, nodeBlocks+edgeBlocks):
// edge MLP (IN=4). Last block: gate-matrix prep + zero gsum/gcnt/counter.
__global__ __launch_bounds__(256) void mlp_prep_kernel(
        const float* __restrict__ node_feat, const float* __restrict__ edge_attr,
        const float* __restrict__ Wn1, const float* __restrict__ bn1,
        const float* __restrict__ Wn2, const float* __restrict__ bn2,
        const float* __restrict__ We1, const float* __restrict__ be1,
        const float* __restrict__ We2, const float* __restrict__ be2,
        const float* __restrict__ strong, const float* __restrict__ inits,
        const float* __restrict__ update,
        float* __restrict__ x, float* __restrict__ e,
        float* __restrict__ gm, float* __restrict__ zbuf, int nzero,
        int N, int NE, int nodeBlocks, int edgeBlocks) {
    int bid = blockIdx.x;
    if (bid < nodeBlocks) {
        int r = bid * 256 + threadIdx.x;
        if (r >= N) return;
        float f[8];
#pragma unroll
        for (int k = 0; k < 8; k++) f[k] = node_feat[r * 8 + k];
        float o0 = bn2[0], o1 = bn2[1];
        for (int j = 0; j < 128; j++) {
            float h = bn1[j];
#pragma unroll
            for (int k = 0; k < 8; k++) h += f[k] * Wn1[k * 128 + j];
            h = h > 0.f ? h : 0.01f * h;
            o0 += h * Wn2[j * 2 + 0];
            o1 += h * Wn2[j * 2 + 1];
        }
        x[r * 2 + 0] = tanhf(o0) * PI_F;
        x[r * 2 + 1] = tanhf(o1) * PI_F;
    } else if (bid < nodeBlocks + edgeBlocks) {
        int r = (bid - nodeBlocks) * 256 + threadIdx.x;
        if (r >= NE) return;
        float f[4];
#pragma unroll
        for (int k = 0; k < 4; k++) f[k] = edge_attr[r * 4 + k];
        float o0 = be2[0], o1 = be2[1];
        for (int j = 0; j < 128; j++) {
            float h = be1[j];
#pragma unroll
            for (int k = 0; k < 4; k++) h += f[k] * We1[k * 128 + j];
            h = h > 0.f ? h : 0.01f * h;
            o0 += h * We2[j * 2 + 0];
            o1 += h * We2[j * 2 + 1];
        }
        e[r * 2 + 0] = tanhf(o0) * PI_F;
        e[r * 2 + 1] = tanhf(o1) * PI_F;
    } else {
        int j = threadIdx.x;
        if (j < 4) {
            gm[2 * j]     = cosf(0.5f * inits[j]);
            gm[2 * j + 1] = sinf(0.5f * inits[j]);
        } else if (j < 13) {
            const float* w;
            if (j < 7)       w = strong + (j - 4) * 3;
            else if (j < 10) w = strong + 9 + (j - 7) * 3;
            else             w = update + (j - 10) * 3;
            M4 M = mrot(w[0], w[1], w[2]);
            float* o = gm + 8 + (j - 4) * 8;
            o[0] = M.u00.x; o[1] = M.u00.y; o[2] = M.u01.x; o[3] = M.u01.y;
            o[4] = M.u10.x; o[5] = M.u10.y; o[6] = M.u11.x; o[7] = M.u11.y;
        }
        for (int i = j; i < nzero; i += 256) zbuf[i] = 0.f;
    }
}

// ---------- kernel B: PQC + update-MLP + pooling + head, fused ----------
// One wave per sample; 4 waves per block. expval stays in registers; the
// update MLP is wave-parallel (2 hidden units/lane); pooling via LDS bins ->
// nonzero-bin global atomics; ticketed last block computes the head.
#define MAX_GRAPHS 64
__global__ __launch_bounds__(256) void pqc_fused_kernel(
        const float* __restrict__ x, const float* __restrict__ e,
        const int* __restrict__ subgraphs, const int* __restrict__ edge_ids,
        const int* __restrict__ batch, const float* __restrict__ gm,
        const float* __restrict__ Wu1, const float* __restrict__ bu1,
        const float* __restrict__ Wu2, const float* __restrict__ bu2,
        const float* __restrict__ Wh1, const float* __restrict__ bh1,
        const float* __restrict__ Wh2, const float* __restrict__ bh2,
        float* __restrict__ gsum, float* __restrict__ gcnt,
        unsigned int* __restrict__ counter, float* __restrict__ out,
        int ntot, int ngraphs) {
    __shared__ float bins[3 * MAX_GRAPHS];
    __shared__ bool isLast;
    for (int i = threadIdx.x; i < 3 * ngraphs; i += 256) bins[i] = 0.f;
    __syncthreads();

    int wave = threadIdx.x >> 6;
    int lane = threadIdx.x & 63;
    int s = blockIdx.x * 4 + wave;
    bool active = s < ntot;

    if (active) {
        // angles: rows 0..2 = e[edge_ids[s]], rows 3..6 = x[subgraphs[s]]
        float ang[7][2];
        int cidx = subgraphs[s * 4];
        for (int j = 0; j < 3; j++) {
            int eid = edge_ids[s * 3 + j];
            ang[j][0] = e[2 * eid]; ang[j][1] = e[2 * eid + 1];
        }
        ang[3][0] = x[2 * cidx]; ang[3][1] = x[2 * cidx + 1];
        for (int j = 1; j < 4; j++) {
            int nid = subgraphs[s * 4 + j];
            ang[3 + j][0] = x[2 * nid]; ang[3 + j][1] = x[2 * nid + 1];
        }

        // Encoding layer on |0..0>: closed-form product state.
        float2 c = make_float2(1.f, 0.f);
#pragma unroll
        for (int w = 0; w < 6; w++) {
            float a = 0.5f * ang[w][0], b = 0.5f * ang[w][1];
            float ca = __cosf(a), sa = __sinf(a);
            float cb = __cosf(b), sb = __sinf(b);
            float2 v0 = make_float2(ca * cb, -ca * sb);
            float2 v1 = make_float2(sa * cb,  sa * sb);
            int bit = (lane >> (5 - w)) & 1;
            c = cmul2(c, bit ? v1 : v0);
        }
        float2 amp[8];
#pragma unroll
        for (int r = 0; r < 8; r++) amp[r] = make_float2(0.f, 0.f);
        {
            float a = 0.5f * ang[6][0], b = 0.5f * ang[6][1];
            float ca = __cosf(a), sa = __sinf(a);
            float cb = __cosf(b), sb = __sinf(b);
            amp[0] = cmul2(c, make_float2(ca * cb, -ca * sb));
            amp[4] = cmul2(c, make_float2(sa * cb,  sa * sb));
        }

        float cx  = gm[0], sx  = gm[1];
        float cy1 = gm[2], sy1 = gm[3];
        float cz  = gm[4], sz  = gm[5];
        float cy2 = gm[6], sy2 = gm[7];

        block_i<0>(amp, cx, sx, cy1, sy1, cz, sz, cy2, sy2, gm, lane);
        block_i<1>(amp, cx, sx, cy1, sy1, cz, sz, cy2, sy2, gm, lane);
        block_i<2>(amp, cx, sx, cy1, sy1, cz, sz, cy2, sy2, gm, lane);
        sel3m<3, 7, 8>(gm + 56, amp, lane);

        // <X_3>: butterfly so ALL lanes hold the expval
        float acc = 0.f;
#pragma unroll
        for (int r = 0; r < 8; r++) {
            float2 o = shflx(amp[r], 4);
            acc += amp[r].x * o.x + amp[r].y * o.y;
        }
        for (int off = 32; off > 0; off >>= 1) acc += __shfl_xor(acc, off, 64);

        // update MLP [f0,f1,f2] -> 128 -> 2, wave-parallel (units lane, lane+64)
        float f0 = ang[3][0], f1 = ang[3][1], f2 = acc;
        int j1 = lane, j2 = lane + 64;
        float h1 = bu1[j1] + f0 * Wu1[j1] + f1 * Wu1[128 + j1] + f2 * Wu1[256 + j1];
        float h2 = bu1[j2] + f0 * Wu1[j2] + f1 * Wu1[128 + j2] + f2 * Wu1[256 + j2];
        h1 = h1 > 0.f ? h1 : 0.01f * h1;
        h2 = h2 > 0.f ? h2 : 0.01f * h2;
        float o0 = h1 * Wu2[2 * j1]     + h2 * Wu2[2 * j2];
        float o1 = h1 * Wu2[2 * j1 + 1] + h2 * Wu2[2 * j2 + 1];
        for (int off = 32; off > 0; off >>= 1) {
            o0 += __shfl_down(o0, off, 64);
            o1 += __shfl_down(o1, off, 64);
        }
        if (lane == 0) {
            o0 += bu2[0]; o1 += bu2[1];
            int bs = batch[s], bc = batch[cidx];
            // node term x[s] + count
            atomicAdd(&bins[3 * bs + 0], x[2 * s + 0]);
            atomicAdd(&bins[3 * bs + 1], x[2 * s + 1]);
            atomicAdd(&bins[3 * bs + 2], 1.f);
            // update term at center's graph
            atomicAdd(&bins[3 * bc + 0], o0);
            atomicAdd(&bins[3 * bc + 1], o1);
        }
    }
    __syncthreads();

    // flush non-zero bins (typically 1 graph per block)
    for (int i = threadIdx.x; i < ngraphs; i += 256) {
        float s0 = bins[3 * i + 0], s1 = bins[3 * i + 1], sc = bins[3 * i + 2];
        if (s0 != 0.f || s1 != 0.f || sc != 0.f) {
            atomicAdd(&gsum[2 * i + 0], s0);
            atomicAdd(&gsum[2 * i + 1], s1);
            atomicAdd(&gcnt[i], sc);
        }
    }

    // ticket: last block computes the head
    __threadfence();
    if (threadIdx.x == 0) {
        unsigned int t = atomicAdd(counter, 1u);
        isLast = (t == gridDim.x - 1);
    }
    __syncthreads();
    if (isLast) {
        int g = threadIdx.x;
        if (g < ngraphs) {
            // read via device-scope atomics (bypass possibly-stale L1)
            float cgs = atomicAdd(&gcnt[g], 0.f);
            float g0 = atomicAdd(&gsum[2 * g + 0], 0.f) / cgs;
            float g1 = atomicAdd(&gsum[2 * g + 1], 0.f) / cgs;
            float h0 = g0 * Wh1[0] + g1 * Wh1[2] + bh1[0];
            float h1 = g0 * Wh1[1] + g1 * Wh1[3] + bh1[1];
            h0 = h0 > 0.f ? h0 : 0.01f * h0;
            h1 = h1 > 0.f ? h1 : 0.01f * h1;
            out[2 * g + 0] = h0 * Wh2[0] + h1 * Wh2[2] + bh2[0];
            out[2 * g + 1] = h0 * Wh2[1] + h1 * Wh2[3] + bh2[1];
        }
    }
}

extern "C" void kernel_launch(void* const* d_in, const int* in_sizes, int n_in,
                              void* d_out, int out_size, void* d_ws, size_t ws_size,
                              hipStream_t stream) {
    const float* node_feat = (const float*)d_in[0];   // (N, 8)
    const float* edge_attr = (const float*)d_in[1];   // (3N, 4)
    const float* Wn1 = (const float*)d_in[2];
    const float* bn1 = (const float*)d_in[3];
    const float* Wn2 = (const float*)d_in[4];
    const float* bn2 = (const float*)d_in[5];
    const float* We1 = (const float*)d_in[6];
    const float* be1 = (const float*)d_in[7];
    const float* We2 = (const float*)d_in[8];
    const float* be2 = (const float*)d_in[9];
    const float* strong = (const float*)d_in[10];     // (2,1,3,3)
    const float* inits  = (const float*)d_in[11];     // (1,4)
    const float* update = (const float*)d_in[12];     // (1,3,3)
    const float* Wu1 = (const float*)d_in[13];
    const float* bu1 = (const float*)d_in[14];
    const float* Wu2 = (const float*)d_in[15];
    const float* bu2 = (const float*)d_in[16];
    const float* Wh1 = (const float*)d_in[17];
    const float* bh1 = (const float*)d_in[18];
    const float* Wh2 = (const float*)d_in[19];
    const float* bh2 = (const float*)d_in[20];
    const int* subgraphs = (const int*)d_in[21];      // (N, 4)
    const int* edge_ids  = (const int*)d_in[22];      // (N, 3)
    const int* batch     = (const int*)d_in[23];      // (N,)

    const int N  = in_sizes[0] / 8;      // 4096 nodes
    const int NE = in_sizes[1] / 4;      // 12288 edges
    const int NG = out_size / 2;         // 16 graphs

    // workspace layout (floats)
    float* ws   = (float*)d_ws;
    float* x    = ws;                    // N*2
    float* e    = x + (size_t)N * 2;     // NE*2
    float* gsum = e + (size_t)NE * 2;    // NG*2
    float* gcnt = gsum + (size_t)NG * 2; // NG       (contiguous with gsum)
    float* ctrf = gcnt + NG;             // 1 float slot used as uint counter
    float* gm   = ctrf + 1;              // 80 floats of gate data

    int nodeBlocks = (N + 255) / 256;
    int edgeBlocks = (NE + 255) / 256;

    // Kernel A: MLPs + prep block (zeroes gsum, gcnt, counter = 3*NG+1 floats)
    mlp_prep_kernel<<<nodeBlocks + edgeBlocks + 1, 256, 0, stream>>>(
        node_feat, edge_attr, Wn1, bn1, Wn2, bn2, We1, be1, We2, be2,
        strong, inits, update, x, e, gm, gsum, 3 * NG + 1, N, NE, nodeBlocks, edgeBlocks);

    // Kernel B: PQC + update MLP + pooling + head
    pqc_fused_kernel<<<(N + 3) / 4, 256, 0, stream>>>(
        x, e, subgraphs, edge_ids, batch, gm, Wu1, bu1, Wu2, bu2,
        Wh1, bh1, Wh2, bh2, gsum, gcnt, (unsigned int*)ctrf, (float*)d_out, N, NG);
}

// Round 7
// 149.963 us; speedup vs baseline: 1.2401x; 1.2401x over previous
//
#include <hip/hip_runtime.h>
#include <math.h>

#define PI_F 3.14159265358979323846f

// ---------- complex helpers (float2 as complex) ----------
__device__ __forceinline__ float2 cmul2(float2 a, float2 b) {
    return make_float2(a.x * b.x - a.y * b.y, a.x * b.y + a.y * b.x);
}
// u*a + v*b
__device__ __forceinline__ float2 cmac2(float2 u, float2 a, float2 v, float2 b) {
    float2 r;
    r.x = u.x * a.x - u.y * a.y + v.x * b.x - v.y * b.y;
    r.y = u.x * a.y + u.y * a.x + v.x * b.y + v.y * b.x;
    return r;
}

struct M4 { float2 u00, u01, u10, u11; };

__device__ __forceinline__ M4 mmul4(const M4& A, const M4& B) {
    M4 R;
    R.u00 = cmac2(A.u00, B.u00, A.u01, B.u10);
    R.u01 = cmac2(A.u00, B.u01, A.u01, B.u11);
    R.u10 = cmac2(A.u10, B.u00, A.u11, B.u10);
    R.u11 = cmac2(A.u10, B.u01, A.u11, B.u11);
    return R;
}
__device__ __forceinline__ M4 mry(float t) {
    float c = cosf(0.5f * t), s = sinf(0.5f * t);
    M4 R; R.u00 = {c, 0}; R.u01 = {-s, 0}; R.u10 = {s, 0}; R.u11 = {c, 0};
    return R;
}
__device__ __forceinline__ M4 mrz(float t) {
    float c = cosf(0.5f * t), s = sinf(0.5f * t);
    M4 R; R.u00 = {c, -s}; R.u01 = {0, 0}; R.u10 = {0, 0}; R.u11 = {c, s};
    return R;
}
// Rot(phi, theta, omega) = RZ(omega) @ RY(theta) @ RZ(phi)
__device__ __forceinline__ M4 mrot(float phi, float th, float om) {
    return mmul4(mmul4(mrz(om), mry(th)), mrz(phi));
}

__device__ __forceinline__ float2 shflx(float2 v, int mask) {
    return make_float2(__shfl_xor(v.x, mask, 64), __shfl_xor(v.y, mask, 64));
}

// load an M4 from wave-uniform global memory (compiler emits scalar loads)
__device__ __forceinline__ M4 ldm(const float* __restrict__ g) {
    M4 M;
    M.u00 = make_float2(g[0], g[1]); M.u01 = make_float2(g[2], g[3]);
    M.u10 = make_float2(g[4], g[5]); M.u11 = make_float2(g[6], g[7]);
    return M;
}

// ---------- register statevector: idx = lane*8 + r ----------
// idx bit b: b in [0,2] -> register bit b; b in [3,8] -> lane bit (b-3).
// wire w -> idx bit (8-w). Wires 0..5 = lane bits 5..0; wires 6,7,8 = reg bits 2,1,0.

// single-qubit dense gate on register bit TB
template <int TB>
__device__ __forceinline__ void rot_reg(const M4& U, float2 (&amp)[8]) {
#pragma unroll
    for (int r = 0; r < 8; r++)
        if (((r >> TB) & 1) == 0) {
            int r1 = r | (1 << TB);
            float2 a = amp[r], b = amp[r1];
            amp[r]  = cmac2(U.u00, a, U.u01, b);
            amp[r1] = cmac2(U.u10, a, U.u11, b);
        }
}

// single-qubit dense gate on lane bit LB
template <int LB>
__device__ __forceinline__ void rot_lane(const M4& U, float2 (&amp)[8], int lane) {
    bool hi = (lane >> LB) & 1;
    float2 cA = hi ? U.u11 : U.u00;
    float2 cB = hi ? U.u10 : U.u01;
#pragma unroll
    for (int r = 0; r < 8; r++) {
        float2 o = shflx(amp[r], 1 << LB);
        amp[r] = cmac2(cA, amp[r], cB, o);
    }
}

template <int WIRE>
__device__ __forceinline__ void rot1(const M4& U, float2 (&amp)[8], int lane) {
    constexpr int BIT = 8 - WIRE;
    if constexpr (BIT < 3) rot_reg<BIT>(U, amp);
    else rot_lane<BIT - 3>(U, amp, lane);
}

// ---------- specialized controlled rotations (target = reg bit TB) ----------

// controlled RX: [[c, -i s], [-i s, c]]
template <int CBIT, int TB>
__device__ __forceinline__ void crx_g(float c, float s, float2 (&amp)[8], int lane) {
    if constexpr (CBIT >= 3) {
        bool ct = (lane >> (CBIT - 3)) & 1;
        float cc = ct ? c : 1.f, ss = ct ? s : 0.f;
#pragma unroll
        for (int r = 0; r < 8; r++)
            if (((r >> TB) & 1) == 0) {
                int r1 = r | (1 << TB);
                float2 a = amp[r], b = amp[r1];
                amp[r]  = make_float2(cc * a.x + ss * b.y, cc * a.y - ss * b.x);
                amp[r1] = make_float2(ss * a.y + cc * b.x, cc * b.y - ss * a.x);
            }
    } else {
#pragma unroll
        for (int r = 0; r < 8; r++)
            if (((r >> CBIT) & 1) == 1 && ((r >> TB) & 1) == 0) {
                int r1 = r | (1 << TB);
                float2 a = amp[r], b = amp[r1];
                amp[r]  = make_float2(c * a.x + s * b.y, c * a.y - s * b.x);
                amp[r1] = make_float2(s * a.y + c * b.x, c * b.y - s * a.x);
            }
    }
}

// controlled RY: [[c, -s], [s, c]] (real)
template <int CBIT, int TB>
__device__ __forceinline__ void cry_g(float c, float s, float2 (&amp)[8], int lane) {
    if constexpr (CBIT >= 3) {
        bool ct = (lane >> (CBIT - 3)) & 1;
        float cc = ct ? c : 1.f, ss = ct ? s : 0.f;
#pragma unroll
        for (int r = 0; r < 8; r++)
            if (((r >> TB) & 1) == 0) {
                int r1 = r | (1 << TB);
                float2 a = amp[r], b = amp[r1];
                amp[r]  = make_float2(cc * a.x - ss * b.x, cc * a.y - ss * b.y);
                amp[r1] = make_float2(ss * a.x + cc * b.x, ss * a.y + cc * b.y);
            }
    } else {
#pragma unroll
        for (int r = 0; r < 8; r++)
            if (((r >> CBIT) & 1) == 1 && ((r >> TB) & 1) == 0) {
                int r1 = r | (1 << TB);
                float2 a = amp[r], b = amp[r1];
                amp[r]  = make_float2(c * a.x - s * b.x, c * a.y - s * b.y);
                amp[r1] = make_float2(s * a.x + c * b.x, s * a.y + c * b.y);
            }
    }
}

// controlled RZ: diag(e, conj(e)), e = c - i s
template <int CBIT, int TB>
__device__ __forceinline__ void crz_g(float c, float s, float2 (&amp)[8], int lane) {
    if constexpr (CBIT >= 3) {
        bool ct = (lane >> (CBIT - 3)) & 1;
        float cc = ct ? c : 1.f, ss = ct ? s : 0.f;
#pragma unroll
        for (int r = 0; r < 8; r++)
            if (((r >> TB) & 1) == 0) {
                int r1 = r | (1 << TB);
                float2 a = amp[r], b = amp[r1];
                amp[r]  = make_float2(cc * a.x + ss * a.y, cc * a.y - ss * a.x);
                amp[r1] = make_float2(cc * b.x - ss * b.y, cc * b.y + ss * b.x);
            }
    } else {
#pragma unroll
        for (int r = 0; r < 8; r++)
            if (((r >> CBIT) & 1) == 1 && ((r >> TB) & 1) == 0) {
                int r1 = r | (1 << TB);
                float2 a = amp[r], b = amp[r1];
                amp[r]  = make_float2(c * a.x + s * a.y, c * a.y - s * a.x);
                amp[r1] = make_float2(c * b.x - s * b.y, c * b.y + s * b.x);
            }
    }
}

template <int CW, int TW>
__device__ __forceinline__ void cnotg(float2 (&amp)[8], int lane) {
    constexpr int CBIT = 8 - CW, TBIT = 8 - TW;
    if constexpr (CBIT < 3 && TBIT < 3) {
#pragma unroll
        for (int r = 0; r < 8; r++)
            if (((r >> CBIT) & 1) == 1 && ((r >> TBIT) & 1) == 0) {
                int r1 = r | (1 << TBIT);
                float2 t = amp[r]; amp[r] = amp[r1]; amp[r1] = t;
            }
    } else if constexpr (CBIT >= 3 && TBIT < 3) {
        bool c = (lane >> (CBIT - 3)) & 1;
#pragma unroll
        for (int r = 0; r < 8; r++)
            if (((r >> TBIT) & 1) == 0) {
                int r1 = r | (1 << TBIT);
                float2 t0 = amp[r], t1 = amp[r1];
                amp[r]  = c ? t1 : t0;
                amp[r1] = c ? t0 : t1;
            }
    } else if constexpr (CBIT < 3 && TBIT >= 3) {
#pragma unroll
        for (int r = 0; r < 8; r++)
            if (((r >> CBIT) & 1) == 1) {
                amp[r] = shflx(amp[r], 1 << (TBIT - 3));
            }
    } else {
        bool c = (lane >> (CBIT - 3)) & 1;
#pragma unroll
        for (int r = 0; r < 8; r++) {
            float2 o = shflx(amp[r], 1 << (TBIT - 3));
            amp[r] = c ? o : amp[r];
        }
    }
}

// StronglyEntanglingLayers, L=1, 3 wires; gm = 3 precomputed dense Rot matrices
template <int W0, int W1, int W2>
__device__ __forceinline__ void sel3m(const float* __restrict__ gm, float2 (&amp)[8], int lane) {
    rot1<W0>(ldm(gm),      amp, lane);
    rot1<W1>(ldm(gm + 8),  amp, lane);
    rot1<W2>(ldm(gm + 16), amp, lane);
    cnotg<W0, W1>(amp, lane);
    cnotg<W1, W2>(amp, lane);
    cnotg<W2, W0>(amp, lane);
}

// gm layout (floats): [0..7] (c,s) x4 ctrl gates; [8..31] strong[0]; [32..55] strong[1]; [56..79] update
template <int I>
__device__ __forceinline__ void block_i(float2 (&amp)[8], float cx, float sx, float cy1, float sy1,
                                        float cz, float sz, float cy2, float sy2,
                                        const float* __restrict__ gm, int lane) {
    crx_g<4 - I, 1>(cx,  sx,  amp, lane);
    cry_g<8 - I, 1>(cy1, sy1, amp, lane);
    crz_g<4 - I, 0>(cz,  sz,  amp, lane);
    cry_g<8 - I, 0>(cy2, sy2, amp, lane);
    sel3m<I, 4 + I, 7>(gm + 8,  amp, lane);   // strong[0]
    sel3m<7, 4 + I, 8>(gm + 32, amp, lane);   // strong[1]
}

// ---------- kernel A: feature MLPs + prep block ----------
__global__ __launch_bounds__(256) void mlp_prep_kernel(
        const float* __restrict__ node_feat, const float* __restrict__ edge_attr,
        const float* __restrict__ Wn1, const float* __restrict__ bn1,
        const float* __restrict__ Wn2, const float* __restrict__ bn2,
        const float* __restrict__ We1, const float* __restrict__ be1,
        const float* __restrict__ We2, const float* __restrict__ be2,
        const float* __restrict__ strong, const float* __restrict__ inits,
        const float* __restrict__ update,
        float* __restrict__ x, float* __restrict__ e,
        float* __restrict__ gm, float* __restrict__ zbuf, int nzero,
        int N, int NE, int nodeBlocks, int edgeBlocks) {
    int bid = blockIdx.x;
    if (bid < nodeBlocks) {
        int r = bid * 256 + threadIdx.x;
        if (r >= N) return;
        float f[8];
#pragma unroll
        for (int k = 0; k < 8; k++) f[k] = node_feat[r * 8 + k];
        float o0 = bn2[0], o1 = bn2[1];
        for (int j = 0; j < 128; j++) {
            float h = bn1[j];
#pragma unroll
            for (int k = 0; k < 8; k++) h += f[k] * Wn1[k * 128 + j];
            h = h > 0.f ? h : 0.01f * h;
            o0 += h * Wn2[j * 2 + 0];
            o1 += h * Wn2[j * 2 + 1];
        }
        x[r * 2 + 0] = tanhf(o0) * PI_F;
        x[r * 2 + 1] = tanhf(o1) * PI_F;
    } else if (bid < nodeBlocks + edgeBlocks) {
        int r = (bid - nodeBlocks) * 256 + threadIdx.x;
        if (r >= NE) return;
        float f[4];
#pragma unroll
        for (int k = 0; k < 4; k++) f[k] = edge_attr[r * 4 + k];
        float o0 = be2[0], o1 = be2[1];
        for (int j = 0; j < 128; j++) {
            float h = be1[j];
#pragma unroll
            for (int k = 0; k < 4; k++) h += f[k] * We1[k * 128 + j];
            h = h > 0.f ? h : 0.01f * h;
            o0 += h * We2[j * 2 + 0];
            o1 += h * We2[j * 2 + 1];
        }
        e[r * 2 + 0] = tanhf(o0) * PI_F;
        e[r * 2 + 1] = tanhf(o1) * PI_F;
    } else {
        int j = threadIdx.x;
        if (j < 4) {
            gm[2 * j]     = cosf(0.5f * inits[j]);
            gm[2 * j + 1] = sinf(0.5f * inits[j]);
        } else if (j < 13) {
            const float* w;
            if (j < 7)       w = strong + (j - 4) * 3;
            else if (j < 10) w = strong + 9 + (j - 7) * 3;
            else             w = update + (j - 10) * 3;
            M4 M = mrot(w[0], w[1], w[2]);
            float* o = gm + 8 + (j - 4) * 8;
            o[0] = M.u00.x; o[1] = M.u00.y; o[2] = M.u01.x; o[3] = M.u01.y;
            o[4] = M.u10.x; o[5] = M.u10.y; o[6] = M.u11.x; o[7] = M.u11.y;
        }
        for (int i = j; i < nzero; i += 256) zbuf[i] = 0.f;
    }
}

// ---------- kernel B: PQC + update-MLP + pooling (NO fence, NO in-kernel head) ----------
// One wave per sample; 4 waves per block. expval stays in registers; the
// update MLP is wave-parallel; pooling via LDS bins -> nonzero-bin atomics.
// The head runs as a separate tiny kernel: stream ordering provides the
// cross-XCD coherence that an in-kernel __threadfence ticket made pathological
// (R5 regression: per-wave agent-scope fences serialized at the TCCs).
#define MAX_GRAPHS 64
__global__ __launch_bounds__(256) void pqc_fused_kernel(
        const float* __restrict__ x, const float* __restrict__ e,
        const int* __restrict__ subgraphs, const int* __restrict__ edge_ids,
        const int* __restrict__ batch, const float* __restrict__ gm,
        const float* __restrict__ Wu1, const float* __restrict__ bu1,
        const float* __restrict__ Wu2, const float* __restrict__ bu2,
        float* __restrict__ gsum, float* __restrict__ gcnt,
        int ntot, int ngraphs) {
    __shared__ float bins[3 * MAX_GRAPHS];
    for (int i = threadIdx.x; i < 3 * ngraphs; i += 256) bins[i] = 0.f;
    __syncthreads();

    int wave = threadIdx.x >> 6;
    int lane = threadIdx.x & 63;
    int s = blockIdx.x * 4 + wave;
    bool active = s < ntot;

    if (active) {
        // angles: rows 0..2 = e[edge_ids[s]], rows 3..6 = x[subgraphs[s]]
        float ang[7][2];
        int cidx = subgraphs[s * 4];
        for (int j = 0; j < 3; j++) {
            int eid = edge_ids[s * 3 + j];
            ang[j][0] = e[2 * eid]; ang[j][1] = e[2 * eid + 1];
        }
        ang[3][0] = x[2 * cidx]; ang[3][1] = x[2 * cidx + 1];
        for (int j = 1; j < 4; j++) {
            int nid = subgraphs[s * 4 + j];
            ang[3 + j][0] = x[2 * nid]; ang[3 + j][1] = x[2 * nid + 1];
        }

        // Encoding layer on |0..0>: closed-form product state.
        float2 c = make_float2(1.f, 0.f);
#pragma unroll
        for (int w = 0; w < 6; w++) {
            float a = 0.5f * ang[w][0], b = 0.5f * ang[w][1];
            float ca = __cosf(a), sa = __sinf(a);
            float cb = __cosf(b), sb = __sinf(b);
            float2 v0 = make_float2(ca * cb, -ca * sb);
            float2 v1 = make_float2(sa * cb,  sa * sb);
            int bit = (lane >> (5 - w)) & 1;
            c = cmul2(c, bit ? v1 : v0);
        }
        float2 amp[8];
#pragma unroll
        for (int r = 0; r < 8; r++) amp[r] = make_float2(0.f, 0.f);
        {
            float a = 0.5f * ang[6][0], b = 0.5f * ang[6][1];
            float ca = __cosf(a), sa = __sinf(a);
            float cb = __cosf(b), sb = __sinf(b);
            amp[0] = cmul2(c, make_float2(ca * cb, -ca * sb));
            amp[4] = cmul2(c, make_float2(sa * cb,  sa * sb));
        }

        float cx  = gm[0], sx  = gm[1];
        float cy1 = gm[2], sy1 = gm[3];
        float cz  = gm[4], sz  = gm[5];
        float cy2 = gm[6], sy2 = gm[7];

        block_i<0>(amp, cx, sx, cy1, sy1, cz, sz, cy2, sy2, gm, lane);
        block_i<1>(amp, cx, sx, cy1, sy1, cz, sz, cy2, sy2, gm, lane);
        block_i<2>(amp, cx, sx, cy1, sy1, cz, sz, cy2, sy2, gm, lane);
        sel3m<3, 7, 8>(gm + 56, amp, lane);

        // <X_3>: butterfly so ALL lanes hold the expval
        float acc = 0.f;
#pragma unroll
        for (int r = 0; r < 8; r++) {
            float2 o = shflx(amp[r], 4);
            acc += amp[r].x * o.x + amp[r].y * o.y;
        }
        for (int off = 32; off > 0; off >>= 1) acc += __shfl_xor(acc, off, 64);

        // update MLP [f0,f1,f2] -> 128 -> 2, wave-parallel (units lane, lane+64)
        float f0 = ang[3][0], f1 = ang[3][1], f2 = acc;
        int j1 = lane, j2 = lane + 64;
        float h1 = bu1[j1] + f0 * Wu1[j1] + f1 * Wu1[128 + j1] + f2 * Wu1[256 + j1];
        float h2 = bu1[j2] + f0 * Wu1[j2] + f1 * Wu1[128 + j2] + f2 * Wu1[256 + j2];
        h1 = h1 > 0.f ? h1 : 0.01f * h1;
        h2 = h2 > 0.f ? h2 : 0.01f * h2;
        float o0 = h1 * Wu2[2 * j1]     + h2 * Wu2[2 * j2];
        float o1 = h1 * Wu2[2 * j1 + 1] + h2 * Wu2[2 * j2 + 1];
        for (int off = 32; off > 0; off >>= 1) {
            o0 += __shfl_down(o0, off, 64);
            o1 += __shfl_down(o1, off, 64);
        }
        if (lane == 0) {
            o0 += bu2[0]; o1 += bu2[1];
            int bs = batch[s], bc = batch[cidx];
            atomicAdd(&bins[3 * bs + 0], x[2 * s + 0]);
            atomicAdd(&bins[3 * bs + 1], x[2 * s + 1]);
            atomicAdd(&bins[3 * bs + 2], 1.f);
            atomicAdd(&bins[3 * bc + 0], o0);
            atomicAdd(&bins[3 * bc + 1], o1);
        }
    }
    __syncthreads();

    // flush non-zero bins (typically 1 graph per block)
    for (int i = threadIdx.x; i < ngraphs; i += 256) {
        float s0 = bins[3 * i + 0], s1 = bins[3 * i + 1], sc = bins[3 * i + 2];
        if (s0 != 0.f || s1 != 0.f || sc != 0.f) {
            atomicAdd(&gsum[2 * i + 0], s0);
            atomicAdd(&gsum[2 * i + 1], s1);
            atomicAdd(&gcnt[i], sc);
        }
    }
}

// ---------- kernel C: g = gsum/gcnt; out = mlp(g, 2->2->2) ----------
__global__ void head_kernel(const float* __restrict__ gsum, const float* __restrict__ gcnt,
                            const float* __restrict__ Wh1, const float* __restrict__ bh1,
                            const float* __restrict__ Wh2, const float* __restrict__ bh2,
                            float* __restrict__ out, int ngraphs) {
    int g = threadIdx.x;
    if (g >= ngraphs) return;
    float c = gcnt[g];
    float g0 = gsum[2 * g + 0] / c;
    float g1 = gsum[2 * g + 1] / c;
    float h0 = g0 * Wh1[0] + g1 * Wh1[2] + bh1[0];
    float h1 = g0 * Wh1[1] + g1 * Wh1[3] + bh1[1];
    h0 = h0 > 0.f ? h0 : 0.01f * h0;
    h1 = h1 > 0.f ? h1 : 0.01f * h1;
    out[2 * g + 0] = h0 * Wh2[0] + h1 * Wh2[2] + bh2[0];
    out[2 * g + 1] = h0 * Wh2[1] + h1 * Wh2[3] + bh2[1];
}

extern "C" void kernel_launch(void* const* d_in, const int* in_sizes, int n_in,
                              void* d_out, int out_size, void* d_ws, size_t ws_size,
                              hipStream_t stream) {
    const float* node_feat = (const float*)d_in[0];   // (N, 8)
    const float* edge_attr = (const float*)d_in[1];   // (3N, 4)
    const float* Wn1 = (const float*)d_in[2];
    const float* bn1 = (const float*)d_in[3];
    const float* Wn2 = (const float*)d_in[4];
    const float* bn2 = (const float*)d_in[5];
    const float* We1 = (const float*)d_in[6];
    const float* be1 = (const float*)d_in[7];
    const float* We2 = (const float*)d_in[8];
    const float* be2 = (const float*)d_in[9];
    const float* strong = (const float*)d_in[10];     // (2,1,3,3)
    const float* inits  = (const float*)d_in[11];     // (1,4)
    const float* update = (const float*)d_in[12];     // (1,3,3)
    const float* Wu1 = (const float*)d_in[13];
    const float* bu1 = (const float*)d_in[14];
    const float* Wu2 = (const float*)d_in[15];
    const float* bu2 = (const float*)d_in[16];
    const float* Wh1 = (const float*)d_in[17];
    const float* bh1 = (const float*)d_in[18];
    const float* Wh2 = (const float*)d_in[19];
    const float* bh2 = (const float*)d_in[20];
    const int* subgraphs = (const int*)d_in[21];      // (N, 4)
    const int* edge_ids  = (const int*)d_in[22];      // (N, 3)
    const int* batch     = (const int*)d_in[23];      // (N,)

    const int N  = in_sizes[0] / 8;      // 4096 nodes
    const int NE = in_sizes[1] / 4;      // 12288 edges
    const int NG = out_size / 2;         // 16 graphs

    // workspace layout (floats)
    float* ws   = (float*)d_ws;
    float* x    = ws;                    // N*2
    float* e    = x + (size_t)N * 2;     // NE*2
    float* gsum = e + (size_t)NE * 2;    // NG*2
    float* gcnt = gsum + (size_t)NG * 2; // NG       (contiguous with gsum)
    float* gm   = gcnt + NG;             // 80 floats of gate data

    int nodeBlocks = (N + 255) / 256;
    int edgeBlocks = (NE + 255) / 256;

    // Kernel A: MLPs + prep block (zeroes gsum, gcnt = 3*NG floats)
    mlp_prep_kernel<<<nodeBlocks + edgeBlocks + 1, 256, 0, stream>>>(
        node_feat, edge_attr, Wn1, bn1, Wn2, bn2, We1, be1, We2, be2,
        strong, inits, update, x, e, gm, gsum, 3 * NG, N, NE, nodeBlocks, edgeBlocks);

    // Kernel B: PQC + update MLP + pooling
    pqc_fused_kernel<<<(N + 3) / 4, 256, 0, stream>>>(
        x, e, subgraphs, edge_ids, batch, gm, Wu1, bu1, Wu2, bu2,
        gsum, gcnt, N, NG);

    // Kernel C: head
    head_kernel<<<1, 64, 0, stream>>>(gsum, gcnt, Wh1, bh1, Wh2, bh2, (float*)d_out, NG);
}